// Round 9
// baseline (57.271 us; speedup 1.0000x reference)
//
#include <hip/hip_runtime.h>
#include <hip/hip_bf16.h>
#include <math.h>

typedef __attribute__((ext_vector_type(8))) short bf16x8;
typedef __attribute__((ext_vector_type(4))) float f32x4;

#define HST2 80             // H_T row stride (halfs): 160B, 16B-aligned
#define PLANE_STRIDE 92416  // 304*304 halfs
#define ROW_STRIDE   304    // halfs

// ws layout (bytes) — validated layout
#define WS_IDX   0          // 64 ints
#define WS_LAM   256        // 1 float
#define WS_FRAG  4096       // 64 fid * 2 variants * 64 lanes * 16 halfs * 2B = 262,144
#define WS_IMG   266240     // 12 planes * 304 * 304 * 2B = 2,217,984

#define NB_PREP 542         // ceil(12*304*38 / 256)

__device__ __forceinline__ unsigned f2bf(float f) {
    unsigned u = __builtin_bit_cast(unsigned, f);
    u += 0x7FFFu + ((u >> 16) & 1u);          // RNE
    return u >> 16;
}

__device__ __forceinline__ unsigned pk2(float a, float b) {
    return f2bf(a) | (f2bf(b) << 16);
}

// ---------------- top-k (rank by count) + sigmoid(lambda)  [validated] ----------------
__global__ __launch_bounds__(128) void gmix_topk(const float* __restrict__ cp,
                                                 const float* __restrict__ lp,
                                                 int* __restrict__ idx,
                                                 float* __restrict__ lam) {
    int i = threadIdx.x;
    if (i < 90) {
        float v = cp[i];
        int rank = 0;
        for (int j = 0; j < 90; ++j) {
            float vj = cp[j];
            rank += (vj > v) || (vj == v && j < i);
        }
        if (rank < 64) idx[rank] = i;
    }
    if (i == 0) lam[0] = 1.0f / (1.0f + expf(-lp[0]));
}

// ---------------- prep: image->bf16 padded planes + B-fragment tables [validated] ----------------
__global__ __launch_bounds__(256) void gmix_prep(const float* __restrict__ img,
                                                 const float* __restrict__ kers,
                                                 const int* __restrict__ idx,
                                                 short* __restrict__ wsimg,
                                                 short* __restrict__ frag) {
    const int b   = blockIdx.x;
    const int tid = threadIdx.x;
    if (b < NB_PREP) {
        const int cid = b * 256 + tid;               // 8-half chunks
        if (cid >= 12 * 304 * 38) return;
        const int plane = cid / (304 * 38);
        const int rr    = cid % (304 * 38);
        const int r     = rr / 38;
        const int ch    = rr % 38;
        uint4 o = {0u, 0u, 0u, 0u};
        const int gr = r - 22;
        if (gr >= 0 && gr < 256 && ch >= 3 && ch < 35) {
            const float* sp = img + (size_t)plane * 65536 + gr * 256 + (ch * 8 - 24);
            const float4 v0 = *(const float4*)sp;
            const float4 v1 = *(const float4*)(sp + 4);
            o.x = pk2(v0.x, v0.y);
            o.y = pk2(v0.z, v0.w);
            o.z = pk2(v1.x, v1.y);
            o.w = pk2(v1.z, v1.w);
        }
        *(uint4*)(wsimg + plane * PLANE_STRIDE + r * ROW_STRIDE + ch * 8) = o;
    } else if (tid < 64) {
        // unit = fid*2 + v; v=0: B1[k][j]=tap[k-j-2] (pass1), v=1: B2[k][j]=tap[k-j] (pass2)
        const int unit  = b - NB_PREP;       // 0..127
        const int fid   = unit >> 1;
        const int v     = unit & 1;
        const int f     = idx[fid];
        const int lm    = tid & 15;
        const int lg    = tid >> 4;
        const int shift = v ? 0 : 2;
        short* dst = frag + ((size_t)unit * 64 + tid) * 16;
#pragma unroll
        for (int ka = 0; ka < 2; ++ka)
#pragma unroll
            for (int e = 0; e < 8; ++e) {
                const int k = ka * 32 + lg * 8 + e;
                const int d = k - lm - shift;
                const float t = (d >= 0 && d < 45) ? kers[f * 45 + d] : 0.f;
                dst[ka * 8 + e] = (short)f2bf(t);
            }
    }
}

// ---------------- MFMA separable conv: 32-row bands, A in registers, barrier-free ----------------
// grid: 8 pair-groups * 12 planes * 8 bands * 2 col-halves = 1536 blocks, 512 threads.
// LDS = HT only (40.9 KB) -> 2 blocks/CU. Wave-local HT slices -> zero barriers.
__global__ __launch_bounds__(512, 2) void gmix_mfma(const float* __restrict__ img,
                                                    const short* __restrict__ wsimg,
                                                    const short* __restrict__ frag,
                                                    const float* __restrict__ lamp,
                                                    float* __restrict__ out) {
    __shared__ short HT[2][128 * HST2];        // 40,960 B

    const int tid  = threadIdx.x;
    const int lane = tid & 63;
    const int wv   = tid >> 6;
    const int lm   = lane & 15;
    const int lg   = lane >> 4;

    const int bid   = blockIdx.x;
    const int pg    = bid / 192;               // pair-group 0..7 (pairs 4pg..4pg+3)
    const int rem   = bid % 192;
    const int plane = rem >> 4;                // 0..11
    const int band  = (rem >> 1) & 7;          // 0..7
    const int half  = rem & 1;
    const int r0    = band * 32;

    const float* imgp = img + (size_t)plane * 65536;
    const float  lam  = lamp[0];

    // ---- A fragments from global bf16 ws, held in registers across all 4 pairs ----
    // padded rows r0 + t1*16 + lm (t1<5 -> rows r0..r0+79), cols half*128 + wv*16 + lg*8 (+32)
    const short* abase = wsimg + plane * PLANE_STRIDE + (r0 + lm) * ROW_STRIDE
                       + half * 128 + wv * 16 + lg * 8;
    bf16x8 a0s[5], a1s[5];
#pragma unroll
    for (int t1 = 0; t1 < 5; ++t1) {
        a0s[t1] = *(const bf16x8*)(abase + t1 * 16 * ROW_STRIDE);
        a1s[t1] = *(const bf16x8*)(abase + t1 * 16 * ROW_STRIDE + 32);
    }

    // ---- iv (f32 image) for the combine: pair-invariant ----
    const int ocol = half * 128 + wv * 16 + lg * 4;
    f32x4 ivs[2];
#pragma unroll
    for (int t = 0; t < 2; ++t)
        ivs[t] = *(const f32x4*)(imgp + (r0 + t * 16 + lm) * 256 + ocol);

    // wave-local LDS bases (same for every pair)
    short*       htw = &HT[0][(wv * 16 + lm) * HST2 + lg * 4];
    const short* htr = &HT[0][(wv * 16 + lm) * HST2 + lg * 8];
    const int    FOF = 128 * HST2;             // filter-B offset in halfs

#pragma unroll 1
    for (int i = 0; i < 4; ++i) {
        const int p = pg * 4 + i;

        // B-fragments for both filters, both passes (8 x b128 from L2)
        const short* fbA = frag + (size_t)(2 * p) * 2048;
        const short* fbB = fbA + 2048;
        const bf16x8 bA1_0 = *(const bf16x8*)(fbA + lane * 16);
        const bf16x8 bA1_1 = *(const bf16x8*)(fbA + lane * 16 + 8);
        const bf16x8 bA2_0 = *(const bf16x8*)(fbA + 1024 + lane * 16);
        const bf16x8 bA2_1 = *(const bf16x8*)(fbA + 1024 + lane * 16 + 8);
        const bf16x8 bB1_0 = *(const bf16x8*)(fbB + lane * 16);
        const bf16x8 bB1_1 = *(const bf16x8*)(fbB + lane * 16 + 8);
        const bf16x8 bB2_0 = *(const bf16x8*)(fbB + 1024 + lane * 16);
        const bf16x8 bB2_1 = *(const bf16x8*)(fbB + 1024 + lane * 16 + 8);

        // ---- pass 1: H rows 0..79 -> H_T (bf16, transposed, wave-local slice) ----
#pragma unroll
        for (int t1 = 0; t1 < 5; ++t1) {
            f32x4 accA = {0.f, 0.f, 0.f, 0.f};
            f32x4 accB = {0.f, 0.f, 0.f, 0.f};
            accA = __builtin_amdgcn_mfma_f32_16x16x32_bf16(a0s[t1], bA1_0, accA, 0, 0, 0);
            accB = __builtin_amdgcn_mfma_f32_16x16x32_bf16(a0s[t1], bB1_0, accB, 0, 0, 0);
            accA = __builtin_amdgcn_mfma_f32_16x16x32_bf16(a1s[t1], bA1_1, accA, 0, 0, 0);
            accB = __builtin_amdgcn_mfma_f32_16x16x32_bf16(a1s[t1], bB1_1, accB, 0, 0, 0);
            uint2 pkA, pkB;
            pkA.x = pk2(accA[0], accA[1]);
            pkA.y = pk2(accA[2], accA[3]);
            pkB.x = pk2(accB[0], accB[1]);
            pkB.y = pk2(accB[2], accB[3]);
            *(uint2*)(htw + t1 * 16) = pkA;
            *(uint2*)(htw + FOF + t1 * 16) = pkB;
        }

        // ---- pass 2 (vertical on own H_T slice) + clip + mix + store ----
        float* outp = out + ((size_t)(p * 12 + plane) << 16);
#pragma unroll
        for (int t = 0; t < 2; ++t) {
            const bf16x8 hA0 = *(const bf16x8*)(htr + t * 16);
            const bf16x8 hA1 = *(const bf16x8*)(htr + t * 16 + 32);
            const bf16x8 hB0 = *(const bf16x8*)(htr + FOF + t * 16);
            const bf16x8 hB1 = *(const bf16x8*)(htr + FOF + t * 16 + 32);
            f32x4 aA = {0.f, 0.f, 0.f, 0.f};
            f32x4 aB = {0.f, 0.f, 0.f, 0.f};
            aA = __builtin_amdgcn_mfma_f32_16x16x32_bf16(hA0, bA2_0, aA, 0, 0, 0);
            aB = __builtin_amdgcn_mfma_f32_16x16x32_bf16(hB0, bB2_0, aB, 0, 0, 0);
            aA = __builtin_amdgcn_mfma_f32_16x16x32_bf16(hA1, bA2_1, aA, 0, 0, 0);
            aB = __builtin_amdgcn_mfma_f32_16x16x32_bf16(hB1, bB2_1, aB, 0, 0, 0);

            f32x4 res;
#pragma unroll
            for (int q = 0; q < 4; ++q) {
                float hA = ivs[t][q] - aA[q];
                hA = fminf(fmaxf(hA, -1.f), 1.f);
                float hB = ivs[t][q] - aB[q];
                hB = fminf(fmaxf(hB, -1.f), 1.f);
                res[q] = lam * hA + (1.0f - lam) * hB;
            }
            *(f32x4*)(outp + (r0 + t * 16 + lm) * 256 + ocol) = res;
        }
    }
}

extern "C" void kernel_launch(void* const* d_in, const int* in_sizes, int n_in,
                              void* d_out, int out_size, void* d_ws, size_t ws_size,
                              hipStream_t stream) {
    const float* image   = (const float*)d_in[0];   // [4,3,256,256]
    const float* kernels = (const float*)d_in[1];   // [90,45]
    const float* prompt  = (const float*)d_in[2];   // [90]
    const float* lambdap = (const float*)d_in[3];   // [1]
    float* out = (float*)d_out;                     // [32,4,3,256,256]

    int*   ws_idx  = (int*)d_ws;
    float* ws_lam  = (float*)((char*)d_ws + WS_LAM);
    short* ws_frag = (short*)((char*)d_ws + WS_FRAG);
    short* ws_img  = (short*)((char*)d_ws + WS_IMG);

    gmix_topk<<<1, 128, 0, stream>>>(prompt, lambdap, ws_idx, ws_lam);
    gmix_prep<<<NB_PREP + 128, 256, 0, stream>>>(image, kernels, ws_idx, ws_img, ws_frag);
    gmix_mfma<<<1536, 512, 0, stream>>>(image, ws_img, ws_frag, ws_lam, out);
}

// Round 10
// 48.877 us; speedup vs baseline: 1.1717x; 1.1717x over previous
//
#include <hip/hip_runtime.h>
#include <hip/hip_bf16.h>
#include <math.h>

typedef __attribute__((ext_vector_type(8))) short bf16x8;
typedef __attribute__((ext_vector_type(4))) float f32x4;

#define HST3 120            // H_T row stride (halfs): 240B, 16B-aligned
#define FOF  (64 * HST3)    // filter-B offset in HT (halfs)
#define PLANE_STRIDE 92416  // 304*304 halfs
#define ROW_STRIDE   304    // halfs

// ws layout (bytes)
#define WS_FRAG 0           // 64 fid * 2 variants * 64 lanes * 16 halfs * 2B = 262,144
#define WS_IMG  262144      // 12 planes * 304 * 304 * 2B = 2,217,984

#define NB_PREP 542         // ceil(12*304*38 / 256)

__device__ __forceinline__ unsigned f2bf(float f) {
    unsigned u = __builtin_bit_cast(unsigned, f);
    u += 0x7FFFu + ((u >> 16) & 1u);          // RNE
    return u >> 16;
}

__device__ __forceinline__ unsigned pk2(float a, float b) {
    return f2bf(a) | (f2bf(b) << 16);
}

// ---------------- prep: image->bf16 padded planes + rank + B-fragment tables ----------------
// blocks [0, NB_PREP): image conversion [validated]
// blocks [NB_PREP, NB_PREP+128): frag units with inline rank (smap[rank]=tid, validated math)
__global__ __launch_bounds__(256) void gmix_prep(const float* __restrict__ img,
                                                 const float* __restrict__ kers,
                                                 const float* __restrict__ cp,
                                                 short* __restrict__ wsimg,
                                                 short* __restrict__ frag) {
    __shared__ int smap[64];
    const int b   = blockIdx.x;
    const int tid = threadIdx.x;
    if (b < NB_PREP) {
        const int cid = b * 256 + tid;               // 8-half chunks
        if (cid >= 12 * 304 * 38) return;
        const int plane = cid / (304 * 38);
        const int rr    = cid % (304 * 38);
        const int r     = rr / 38;
        const int ch    = rr % 38;
        uint4 o = {0u, 0u, 0u, 0u};
        const int gr = r - 22;
        if (gr >= 0 && gr < 256 && ch >= 3 && ch < 35) {
            const float* sp = img + (size_t)plane * 65536 + gr * 256 + (ch * 8 - 24);
            const float4 v0 = *(const float4*)sp;
            const float4 v1 = *(const float4*)(sp + 4);
            o.x = pk2(v0.x, v0.y);
            o.y = pk2(v0.z, v0.w);
            o.z = pk2(v1.x, v1.y);
            o.w = pk2(v1.z, v1.w);
        }
        *(uint4*)(wsimg + plane * PLANE_STRIDE + r * ROW_STRIDE + ch * 8) = o;
    } else {
        // rank-by-count (validated): smap[rank] = filter index, JAX top_k order
        if (tid < 90) {
            const float mv = cp[tid];
            int rank = 0;
            for (int j = 0; j < 90; ++j) {
                const float vj = cp[j];
                rank += (vj > mv) || (vj == mv && j < tid);
            }
            if (rank < 64) smap[rank] = tid;
        }
        __syncthreads();
        if (tid < 64) {
            // unit = fid*2 + v; v=0: B1[k][j]=tap[k-j-2] (pass1), v=1: B2[k][j]=tap[k-j]
            const int unit  = b - NB_PREP;       // 0..127
            const int fid   = unit >> 1;
            const int v     = unit & 1;
            const int f     = smap[fid];
            const int lm    = tid & 15;
            const int lg    = tid >> 4;
            const int shift = v ? 0 : 2;
            short* dst = frag + ((size_t)unit * 64 + tid) * 16;
#pragma unroll
            for (int ka = 0; ka < 2; ++ka)
#pragma unroll
                for (int e = 0; e < 8; ++e) {
                    const int k = ka * 32 + lg * 8 + e;
                    const int d = k - lm - shift;
                    const float t = (d >= 0 && d < 45) ? kers[f * 45 + d] : 0.f;
                    dst[ka * 8 + e] = (short)f2bf(t);
                }
        }
    }
}

// ---------------- MFMA separable conv: 64-row bands, 64-col quarters, HT-only LDS ----------------
// grid: 8 pair-groups * 12 planes * 4 bands * 4 col-quarters = 1536 blocks, 256 threads (4 waves).
// LDS = 30,720 B -> 4 blocks/CU; wave-local HT slices -> zero barriers.
__global__ __launch_bounds__(256, 4) void gmix_mfma(const float* __restrict__ img,
                                                    const short* __restrict__ wsimg,
                                                    const short* __restrict__ frag,
                                                    const float* __restrict__ lp,
                                                    float* __restrict__ out) {
    __shared__ short HT[2 * 64 * HST3];        // 30,720 B

    const int tid  = threadIdx.x;
    const int lane = tid & 63;
    const int wv   = tid >> 6;                 // 0..3
    const int lm   = lane & 15;
    const int lg   = lane >> 4;

    const int bid   = blockIdx.x;
    const int pg    = bid / 192;               // pair-group 0..7 (pairs 4pg..4pg+3)
    const int rem   = bid % 192;
    const int plane = rem >> 4;                // 0..11
    const int band  = (rem >> 2) & 3;          // 0..3
    const int qcol  = rem & 3;                 // 0..3
    const int r0    = band * 64;
    const int c0    = qcol * 64;

    const float* imgp = img + (size_t)plane * 65536;
    const float  lam  = 1.f / (1.f + expf(-lp[0]));

    // ---- iv (f32 image) for the combine: pair-invariant ----
    const int ocol = c0 + wv * 16 + lg * 4;
    f32x4 ivs[4];
#pragma unroll
    for (int t = 0; t < 4; ++t)
        ivs[t] = *(const f32x4*)(imgp + (r0 + t * 16 + lm) * 256 + ocol);

    // A base: padded rows r0 + t1*16 + lm, padded cols c0 + wv*16 + lg*8 (+32)
    const short* abase = wsimg + plane * PLANE_STRIDE + (r0 + lm) * ROW_STRIDE
                       + c0 + wv * 16 + lg * 8;

    // wave-local LDS bases (same for every pair)
    short*       htw = &HT[(wv * 16 + lm) * HST3 + lg * 4];
    const short* htr = &HT[(wv * 16 + lm) * HST3 + lg * 8];

#pragma unroll 1
    for (int i = 0; i < 4; ++i) {
        const int p = pg * 4 + i;

        // B-fragments for both filters, both passes (8 x b128 from L2-hot 128KB table)
        const short* fbA = frag + (size_t)(2 * p) * 2048;
        const short* fbB = fbA + 2048;
        const bf16x8 bA1_0 = *(const bf16x8*)(fbA + lane * 16);
        const bf16x8 bA1_1 = *(const bf16x8*)(fbA + lane * 16 + 8);
        const bf16x8 bA2_0 = *(const bf16x8*)(fbA + 1024 + lane * 16);
        const bf16x8 bA2_1 = *(const bf16x8*)(fbA + 1024 + lane * 16 + 8);
        const bf16x8 bB1_0 = *(const bf16x8*)(fbB + lane * 16);
        const bf16x8 bB1_1 = *(const bf16x8*)(fbB + lane * 16 + 8);
        const bf16x8 bB2_0 = *(const bf16x8*)(fbB + 1024 + lane * 16);
        const bf16x8 bB2_1 = *(const bf16x8*)(fbB + 1024 + lane * 16 + 8);

        // ---- pass 1: A from global ws (L2), H rows 0..111 -> H_T (wave-local slice) ----
#pragma unroll
        for (int t1 = 0; t1 < 7; ++t1) {
            const bf16x8 a0 = *(const bf16x8*)(abase + t1 * 16 * ROW_STRIDE);
            const bf16x8 a1 = *(const bf16x8*)(abase + t1 * 16 * ROW_STRIDE + 32);
            f32x4 accA = {0.f, 0.f, 0.f, 0.f};
            f32x4 accB = {0.f, 0.f, 0.f, 0.f};
            accA = __builtin_amdgcn_mfma_f32_16x16x32_bf16(a0, bA1_0, accA, 0, 0, 0);
            accB = __builtin_amdgcn_mfma_f32_16x16x32_bf16(a0, bB1_0, accB, 0, 0, 0);
            accA = __builtin_amdgcn_mfma_f32_16x16x32_bf16(a1, bA1_1, accA, 0, 0, 0);
            accB = __builtin_amdgcn_mfma_f32_16x16x32_bf16(a1, bB1_1, accB, 0, 0, 0);
            uint2 pkA, pkB;
            pkA.x = pk2(accA[0], accA[1]);
            pkA.y = pk2(accA[2], accA[3]);
            pkB.x = pk2(accB[0], accB[1]);
            pkB.y = pk2(accB[2], accB[3]);
            *(uint2*)(htw + t1 * 16) = pkA;
            *(uint2*)(htw + FOF + t1 * 16) = pkB;
        }

        // ---- pass 2 (vertical on own H_T slice) + clip + mix + store ----
        float* outp = out + ((size_t)(p * 12 + plane) << 16);
#pragma unroll
        for (int t = 0; t < 4; ++t) {
            const bf16x8 hA0 = *(const bf16x8*)(htr + t * 16);
            const bf16x8 hA1 = *(const bf16x8*)(htr + t * 16 + 32);
            const bf16x8 hB0 = *(const bf16x8*)(htr + FOF + t * 16);
            const bf16x8 hB1 = *(const bf16x8*)(htr + FOF + t * 16 + 32);
            f32x4 aA = {0.f, 0.f, 0.f, 0.f};
            f32x4 aB = {0.f, 0.f, 0.f, 0.f};
            aA = __builtin_amdgcn_mfma_f32_16x16x32_bf16(hA0, bA2_0, aA, 0, 0, 0);
            aB = __builtin_amdgcn_mfma_f32_16x16x32_bf16(hB0, bB2_0, aB, 0, 0, 0);
            aA = __builtin_amdgcn_mfma_f32_16x16x32_bf16(hA1, bA2_1, aA, 0, 0, 0);
            aB = __builtin_amdgcn_mfma_f32_16x16x32_bf16(hB1, bB2_1, aB, 0, 0, 0);

            f32x4 res;
#pragma unroll
            for (int q = 0; q < 4; ++q) {
                float hA = ivs[t][q] - aA[q];
                hA = fminf(fmaxf(hA, -1.f), 1.f);
                float hB = ivs[t][q] - aB[q];
                hB = fminf(fmaxf(hB, -1.f), 1.f);
                res[q] = lam * hA + (1.0f - lam) * hB;
            }
            *(f32x4*)(outp + (r0 + t * 16 + lm) * 256 + ocol) = res;
        }
    }
}

extern "C" void kernel_launch(void* const* d_in, const int* in_sizes, int n_in,
                              void* d_out, int out_size, void* d_ws, size_t ws_size,
                              hipStream_t stream) {
    const float* image   = (const float*)d_in[0];   // [4,3,256,256]
    const float* kernels = (const float*)d_in[1];   // [90,45]
    const float* prompt  = (const float*)d_in[2];   // [90]
    const float* lambdap = (const float*)d_in[3];   // [1]
    float* out = (float*)d_out;                     // [32,4,3,256,256]

    short* ws_frag = (short*)((char*)d_ws + WS_FRAG);
    short* ws_img  = (short*)((char*)d_ws + WS_IMG);

    gmix_prep<<<NB_PREP + 128, 256, 0, stream>>>(image, kernels, prompt, ws_img, ws_frag);
    gmix_mfma<<<1536, 256, 0, stream>>>(image, ws_img, ws_frag, lambdap, out);
}

// Round 11
// 48.780 us; speedup vs baseline: 1.1741x; 1.0020x over previous
//
#include <hip/hip_runtime.h>
#include <hip/hip_bf16.h>
#include <math.h>

typedef __attribute__((ext_vector_type(8))) short bf16x8;
typedef __attribute__((ext_vector_type(4))) float f32x4;

#define HST3 120            // H_T row stride (halfs): 240B, 16B-aligned
#define FOF  (64 * HST3)    // filter-B offset in HT (halfs)
#define PLANE_STRIDE 92416  // 304*304 halfs
#define ROW_STRIDE   304    // halfs

// ws layout (bytes)
#define WS_FRAG 0           // 64 fid * 2 variants * 64 lanes * 16 halfs * 2B = 262,144
#define WS_IMG  262144      // 12 planes * 304 * 304 * 2B = 2,217,984

#define NB_PREP 542         // ceil(12*304*38 / 256)

__device__ __forceinline__ unsigned f2bf(float f) {
    unsigned u = __builtin_bit_cast(unsigned, f);
    u += 0x7FFFu + ((u >> 16) & 1u);          // RNE
    return u >> 16;
}

__device__ __forceinline__ unsigned pk2(float a, float b) {
    return f2bf(a) | (f2bf(b) << 16);
}

// ---------------- prep: image->bf16 padded planes + rank + B-fragment tables [validated] ----------------
__global__ __launch_bounds__(256) void gmix_prep(const float* __restrict__ img,
                                                 const float* __restrict__ kers,
                                                 const float* __restrict__ cp,
                                                 short* __restrict__ wsimg,
                                                 short* __restrict__ frag) {
    __shared__ int smap[64];
    const int b   = blockIdx.x;
    const int tid = threadIdx.x;
    if (b < NB_PREP) {
        const int cid = b * 256 + tid;               // 8-half chunks
        if (cid >= 12 * 304 * 38) return;
        const int plane = cid / (304 * 38);
        const int rr    = cid % (304 * 38);
        const int r     = rr / 38;
        const int ch    = rr % 38;
        uint4 o = {0u, 0u, 0u, 0u};
        const int gr = r - 22;
        if (gr >= 0 && gr < 256 && ch >= 3 && ch < 35) {
            const float* sp = img + (size_t)plane * 65536 + gr * 256 + (ch * 8 - 24);
            const float4 v0 = *(const float4*)sp;
            const float4 v1 = *(const float4*)(sp + 4);
            o.x = pk2(v0.x, v0.y);
            o.y = pk2(v0.z, v0.w);
            o.z = pk2(v1.x, v1.y);
            o.w = pk2(v1.z, v1.w);
        }
        *(uint4*)(wsimg + plane * PLANE_STRIDE + r * ROW_STRIDE + ch * 8) = o;
    } else {
        if (tid < 90) {
            const float mv = cp[tid];
            int rank = 0;
            for (int j = 0; j < 90; ++j) {
                const float vj = cp[j];
                rank += (vj > mv) || (vj == mv && j < tid);
            }
            if (rank < 64) smap[rank] = tid;
        }
        __syncthreads();
        if (tid < 64) {
            // unit = fid*2 + v; v=0: B1[k][j]=tap[k-j-2] (pass1), v=1: B2[k][j]=tap[k-j]
            const int unit  = b - NB_PREP;       // 0..127
            const int fid   = unit >> 1;
            const int v     = unit & 1;
            const int f     = smap[fid];
            const int lm    = tid & 15;
            const int lg    = tid >> 4;
            const int shift = v ? 0 : 2;
            short* dst = frag + ((size_t)unit * 64 + tid) * 16;
#pragma unroll
            for (int ka = 0; ka < 2; ++ka)
#pragma unroll
                for (int e = 0; e < 8; ++e) {
                    const int k = ka * 32 + lg * 8 + e;
                    const int d = k - lm - shift;
                    const float t = (d >= 0 && d < 45) ? kers[f * 45 + d] : 0.f;
                    dst[ka * 8 + e] = (short)f2bf(t);
                }
        }
    }
}

// ---------------- MFMA separable conv: A-frags hoisted, 8 pairs/block ----------------
// grid: 4 pair-groups(8 pairs) * 12 planes * 4 bands * 4 col-quarters = 768 blocks,
// 256 threads (4 waves) -> exactly 3 blocks/CU, full residency, no tail.
// LDS = HT only (30,720 B); wave-local HT slices -> zero barriers.
__global__ __launch_bounds__(256, 3) void gmix_mfma(const float* __restrict__ img,
                                                    const short* __restrict__ wsimg,
                                                    const short* __restrict__ frag,
                                                    const float* __restrict__ lp,
                                                    float* __restrict__ out) {
    __shared__ short HT[2 * 64 * HST3];        // 30,720 B

    const int tid  = threadIdx.x;
    const int lane = tid & 63;
    const int wv   = tid >> 6;                 // 0..3
    const int lm   = lane & 15;
    const int lg   = lane >> 4;

    const int bid   = blockIdx.x;
    const int pg    = bid / 192;               // pair-group 0..3 (pairs 8pg..8pg+7)
    const int rem   = bid % 192;
    const int plane = rem >> 4;                // 0..11
    const int band  = (rem >> 2) & 3;          // 0..3
    const int qcol  = rem & 3;                 // 0..3
    const int r0    = band * 64;
    const int c0    = qcol * 64;

    const float* imgp = img + (size_t)plane * 65536;
    const float  lam  = 1.f / (1.f + expf(-lp[0]));

    // ---- iv (f32 image) for the combine: pair-invariant ----
    const int ocol = c0 + wv * 16 + lg * 4;
    f32x4 ivs[4];
#pragma unroll
    for (int t = 0; t < 4; ++t)
        ivs[t] = *(const f32x4*)(imgp + (r0 + t * 16 + lm) * 256 + ocol);

    // ---- A fragments hoisted: pair-invariant, loaded ONCE per wave (14 x b128) ----
    // padded rows r0 + t1*16 + lm, padded cols c0 + wv*16 + lg*8 (+32)
    const short* abase = wsimg + plane * PLANE_STRIDE + (r0 + lm) * ROW_STRIDE
                       + c0 + wv * 16 + lg * 8;
    bf16x8 a0s[7], a1s[7];
#pragma unroll
    for (int t1 = 0; t1 < 7; ++t1) {
        a0s[t1] = *(const bf16x8*)(abase + t1 * 16 * ROW_STRIDE);
        a1s[t1] = *(const bf16x8*)(abase + t1 * 16 * ROW_STRIDE + 32);
    }

    // wave-local LDS bases (same for every pair)
    short*       htw = &HT[(wv * 16 + lm) * HST3 + lg * 4];
    const short* htr = &HT[(wv * 16 + lm) * HST3 + lg * 8];

#pragma unroll 1
    for (int i = 0; i < 8; ++i) {
        const int p = pg * 8 + i;

        // B-fragments for both filters, both passes (8 x b128 from L2-hot 128KB table)
        const short* fbA = frag + (size_t)(2 * p) * 2048;
        const short* fbB = fbA + 2048;
        const bf16x8 bA1_0 = *(const bf16x8*)(fbA + lane * 16);
        const bf16x8 bA1_1 = *(const bf16x8*)(fbA + lane * 16 + 8);
        const bf16x8 bA2_0 = *(const bf16x8*)(fbA + 1024 + lane * 16);
        const bf16x8 bA2_1 = *(const bf16x8*)(fbA + 1024 + lane * 16 + 8);
        const bf16x8 bB1_0 = *(const bf16x8*)(fbB + lane * 16);
        const bf16x8 bB1_1 = *(const bf16x8*)(fbB + lane * 16 + 8);
        const bf16x8 bB2_0 = *(const bf16x8*)(fbB + 1024 + lane * 16);
        const bf16x8 bB2_1 = *(const bf16x8*)(fbB + 1024 + lane * 16 + 8);

        // ---- pass 1: A from registers, H rows 0..111 -> H_T (wave-local slice) ----
#pragma unroll
        for (int t1 = 0; t1 < 7; ++t1) {
            f32x4 accA = {0.f, 0.f, 0.f, 0.f};
            f32x4 accB = {0.f, 0.f, 0.f, 0.f};
            accA = __builtin_amdgcn_mfma_f32_16x16x32_bf16(a0s[t1], bA1_0, accA, 0, 0, 0);
            accB = __builtin_amdgcn_mfma_f32_16x16x32_bf16(a0s[t1], bB1_0, accB, 0, 0, 0);
            accA = __builtin_amdgcn_mfma_f32_16x16x32_bf16(a1s[t1], bA1_1, accA, 0, 0, 0);
            accB = __builtin_amdgcn_mfma_f32_16x16x32_bf16(a1s[t1], bB1_1, accB, 0, 0, 0);
            uint2 pkA, pkB;
            pkA.x = pk2(accA[0], accA[1]);
            pkA.y = pk2(accA[2], accA[3]);
            pkB.x = pk2(accB[0], accB[1]);
            pkB.y = pk2(accB[2], accB[3]);
            *(uint2*)(htw + t1 * 16) = pkA;
            *(uint2*)(htw + FOF + t1 * 16) = pkB;
        }

        // ---- pass 2 (vertical on own H_T slice) + clip + mix + store ----
        float* outp = out + ((size_t)(p * 12 + plane) << 16);
#pragma unroll
        for (int t = 0; t < 4; ++t) {
            const bf16x8 hA0 = *(const bf16x8*)(htr + t * 16);
            const bf16x8 hA1 = *(const bf16x8*)(htr + t * 16 + 32);
            const bf16x8 hB0 = *(const bf16x8*)(htr + FOF + t * 16);
            const bf16x8 hB1 = *(const bf16x8*)(htr + FOF + t * 16 + 32);
            f32x4 aA = {0.f, 0.f, 0.f, 0.f};
            f32x4 aB = {0.f, 0.f, 0.f, 0.f};
            aA = __builtin_amdgcn_mfma_f32_16x16x32_bf16(hA0, bA2_0, aA, 0, 0, 0);
            aB = __builtin_amdgcn_mfma_f32_16x16x32_bf16(hB0, bB2_0, aB, 0, 0, 0);
            aA = __builtin_amdgcn_mfma_f32_16x16x32_bf16(hA1, bA2_1, aA, 0, 0, 0);
            aB = __builtin_amdgcn_mfma_f32_16x16x32_bf16(hB1, bB2_1, aB, 0, 0, 0);

            f32x4 res;
#pragma unroll
            for (int q = 0; q < 4; ++q) {
                float hA = ivs[t][q] - aA[q];
                hA = fminf(fmaxf(hA, -1.f), 1.f);
                float hB = ivs[t][q] - aB[q];
                hB = fminf(fmaxf(hB, -1.f), 1.f);
                res[q] = lam * hA + (1.0f - lam) * hB;
            }
            *(f32x4*)(outp + (r0 + t * 16 + lm) * 256 + ocol) = res;
        }
    }
}

extern "C" void kernel_launch(void* const* d_in, const int* in_sizes, int n_in,
                              void* d_out, int out_size, void* d_ws, size_t ws_size,
                              hipStream_t stream) {
    const float* image   = (const float*)d_in[0];   // [4,3,256,256]
    const float* kernels = (const float*)d_in[1];   // [90,45]
    const float* prompt  = (const float*)d_in[2];   // [90]
    const float* lambdap = (const float*)d_in[3];   // [1]
    float* out = (float*)d_out;                     // [32,4,3,256,256]

    short* ws_frag = (short*)((char*)d_ws + WS_FRAG);
    short* ws_img  = (short*)((char*)d_ws + WS_IMG);

    gmix_prep<<<NB_PREP + 128, 256, 0, stream>>>(image, kernels, prompt, ws_img, ws_frag);
    gmix_mfma<<<768, 256, 0, stream>>>(image, ws_img, ws_frag, lambdap, out);
}